// Round 2
// baseline (66.150 us; speedup 1.0000x reference)
//
#include <hip/hip_runtime.h>

#define B  32
#define HW 3136
#define C  256
#define HWC (HW*C)           // 802816
#define CR 16                // C / ratio
#define NCHUNK 16
#define POS_PER_CHUNK (HW/NCHUNK)   // 196
#define ITERS (POS_PER_CHUNK/4)     // 49
#define SEGS 98
#define POS_PER_SEG (HW/SEGS)       // 32

typedef float vf4 __attribute__((ext_vector_type(4)));

// ---------------- Stage 1: partial spatial sums -> partial[b][chunk][c] ----
__global__ __launch_bounds__(256) void se_reduce(const float* __restrict__ in,
                                                 float* __restrict__ partial) {
    const int b     = blockIdx.x >> 4;     // NCHUNK == 16
    const int chunk = blockIdx.x & 15;
    const int t  = threadIdx.x;
    const int c4 = t & 63;                 // channel quad index (C/4 == 64)
    const int g  = t >> 6;                 // position group 0..3

    const vf4* p = (const vf4*)(in + (size_t)b * HWC
                                   + (size_t)(chunk * POS_PER_CHUNK + g) * C)
                   + c4;
    vf4 acc = {0.f, 0.f, 0.f, 0.f};
    #pragma unroll 7
    for (int i = 0; i < ITERS; ++i)
        acc += p[(size_t)i * 4 * (C/4)];

    __shared__ vf4 red[256];
    red[t] = acc;
    __syncthreads();
    if (t < 64) {
        vf4 s = red[t] + red[t+64] + red[t+128] + red[t+192];
        ((vf4*)(partial + ((size_t)b * NCHUNK + chunk) * C))[t] = s;
    }
}

// ------- Stage 2 (fused): per-block redundant excite MLP + scale ----------
__global__ __launch_bounds__(256) void se_scale_fused(const float* __restrict__ in,
                                                      const float* __restrict__ partial,
                                                      const float* __restrict__ W1,
                                                      const float* __restrict__ b1,
                                                      const float* __restrict__ W2,
                                                      const float* __restrict__ b2,
                                                      float* __restrict__ out) {
    const int b   = blockIdx.x / SEGS;
    const int seg = blockIdx.x - b * SEGS;
    const int t   = threadIdx.x;
    __shared__ float sq[C];
    __shared__ float h[CR];
    __shared__ float ex[C];

    // squeeze finish (partials are L2-resident: 512 KB shared by all blocks)
    float s = 0.f;
    const float* pp = partial + (size_t)b * NCHUNK * C + t;
    #pragma unroll
    for (int k = 0; k < NCHUNK; ++k) s += pp[k * C];
    sq[t] = s * (1.0f / HW);
    __syncthreads();

    // dense1 + relu (redundant per block — ~4096 MACs, trivial)
    if (t < CR) {
        float a = b1[t];
        #pragma unroll 8
        for (int c = 0; c < C; ++c) a += sq[c] * W1[c * CR + t];
        h[t] = fmaxf(a, 0.0f);
    }
    __syncthreads();

    // dense2 + sigmoid
    {
        float a = b2[t];
        #pragma unroll
        for (int j = 0; j < CR; ++j) a += h[j] * W2[j * C + t];
        ex[t] = 1.0f / (1.0f + expf(-a));
    }
    __syncthreads();

    // scale 32 positions of this (b, seg); non-temporal stores keep the
    // input resident in L3 instead of being evicted by the output stream.
    const int c4 = t & 63;
    const int g  = t >> 6;
    const size_t base = (size_t)b * HWC + (size_t)(seg * POS_PER_SEG + g) * C;
    const vf4* in4 = (const vf4*)(in + base) + c4;
    vf4*      out4 = (vf4*)(out + base) + c4;
    const vf4 e = ((const vf4*)ex)[c4];
    #pragma unroll
    for (int i = 0; i < POS_PER_SEG/4; ++i) {      // 8 iters, step 4 positions
        vf4 v = in4[(size_t)i * 4 * (C/4)];
        v *= e;
        __builtin_nontemporal_store(v, out4 + (size_t)i * 4 * (C/4));
    }
}

// ---------------- Fallback path (old stage 2 + stage 3), if ws too small ---
__global__ __launch_bounds__(256) void se_excite(const float* __restrict__ partial,
                                                 const float* __restrict__ W1,
                                                 const float* __restrict__ b1,
                                                 const float* __restrict__ W2,
                                                 const float* __restrict__ b2,
                                                 float* __restrict__ exc) {
    const int b = blockIdx.x;
    const int t = threadIdx.x;
    __shared__ float sq[C];
    __shared__ float h[CR];

    float s = 0.f;
    const float* pp = partial + (size_t)b * NCHUNK * C + t;
    #pragma unroll
    for (int k = 0; k < NCHUNK; ++k) s += pp[k * C];
    sq[t] = s * (1.0f / HW);
    __syncthreads();

    if (t < CR) {
        float a = b1[t];
        #pragma unroll 8
        for (int c = 0; c < C; ++c) a += sq[c] * W1[c * CR + t];
        h[t] = fmaxf(a, 0.0f);
    }
    __syncthreads();

    float a = b2[t];
    #pragma unroll
    for (int j = 0; j < CR; ++j) a += h[j] * W2[j * C + t];
    exc[b * C + t] = 1.0f / (1.0f + expf(-a));
}

__global__ __launch_bounds__(256) void se_scale(const float* __restrict__ in,
                                                const float* __restrict__ exc,
                                                float* __restrict__ out, int n4) {
    const int stride = gridDim.x * blockDim.x;
    const vf4* in4  = (const vf4*)in;
    const vf4* exc4 = (const vf4*)exc;
    vf4* out4 = (vf4*)out;
    for (int i = blockIdx.x * blockDim.x + threadIdx.x; i < n4; i += stride) {
        vf4 v = in4[i];
        const int b  = i / (HWC/4);
        const int c4 = i & 63;
        v *= exc4[(b << 6) + c4];
        __builtin_nontemporal_store(v, out4 + i);
    }
}

extern "C" void kernel_launch(void* const* d_in, const int* in_sizes, int n_in,
                              void* d_out, int out_size, void* d_ws, size_t ws_size,
                              hipStream_t stream) {
    const float* in = (const float*)d_in[0];
    const float* W1 = (const float*)d_in[1];
    const float* b1 = (const float*)d_in[2];
    const float* W2 = (const float*)d_in[3];
    const float* b2 = (const float*)d_in[4];
    float* out = (float*)d_out;

    const size_t partial_bytes = (size_t)B * NCHUNK * C * sizeof(float);  // 512 KB

    if (ws_size >= partial_bytes) {
        float* partial = (float*)d_ws;
        se_reduce<<<B * NCHUNK, 256, 0, stream>>>(in, partial);
        se_scale_fused<<<B * SEGS, 256, 0, stream>>>(in, partial, W1, b1, W2, b2, out);
    } else {
        // proven 3-kernel path: partials staged in d_out (overwritten later)
        float* partial = out;
        float* exc = (float*)d_ws;        // 32 KB
        se_reduce<<<B * NCHUNK, 256, 0, stream>>>(in, partial);
        se_excite<<<B, 256, 0, stream>>>(partial, W1, b1, W2, b2, exc);
        se_scale<<<2048, 256, 0, stream>>>(in, exc, out, (B * HWC) / 4);
    }
}